// Round 9
// baseline (795.058 us; speedup 1.0000x reference)
//
#include <hip/hip_runtime.h>

#define N_NODES 50000
#define M_PAD 50048      // N_NODES rounded up to 128
#define N_EDGES 500000
#define HEADS 6
#define CH 64
#define F_HID 384
#define IN_DIM 131
#define K0PAD 160        // layer-0 K padded to multiple of 32
#define CAP 64           // fast-path max degree (P(deg>64) ~ 1e-26 for Poisson(10))
#define NBM 391          // cdiv(N_NODES,128)

static inline int cdiv(int a, int b) { return (a + b - 1) / b; }

typedef __attribute__((ext_vector_type(8))) __bf16 bf16x8;
typedef __attribute__((ext_vector_type(4))) float f32x4;
typedef __attribute__((ext_vector_type(8))) unsigned short us8;
typedef __attribute__((ext_vector_type(8))) _Float16 f16x8;

// round-to-nearest-even fp32 -> bf16 split: v ~= hi + lo
__device__ __forceinline__ void bsplit(float v, unsigned short& h, unsigned short& l) {
  unsigned u = __builtin_bit_cast(unsigned, v);
  unsigned hr = (u + 0x7FFFu + ((u >> 16) & 1u)) >> 16;
  h = (unsigned short)hr;
  float hf = __builtin_bit_cast(float, hr << 16);
  float r = v - hf;
  unsigned u2 = __builtin_bit_cast(unsigned, r);
  unsigned lr = (u2 + 0x7FFFu + ((u2 >> 16) & 1u)) >> 16;
  l = (unsigned short)lr;
}

__device__ __forceinline__ void gload16(const void* g, void* lds) {
  __builtin_amdgcn_global_load_lds((const __attribute__((address_space(1))) void*)g,
                                   (__attribute__((address_space(3))) void*)lds, 16, 0, 0);
}

// ---------------- CSR build ----------------
__global__ void count_kernel(const int* __restrict__ ei, int* __restrict__ deg) {
  int e = blockIdx.x * blockDim.x + threadIdx.x;
  if (e < N_EDGES) atomicAdd(&deg[ei[N_EDGES + e]], 1);
}

__global__ void scan_kernel(const int* __restrict__ deg, int* __restrict__ off) {
  __shared__ int sdata[256];
  int tid = threadIdx.x;
  int carry = 0;
  if (tid == 0) off[0] = 0;
  for (int base = 0; base < N_NODES; base += 1024) {
    int idx0 = base + tid * 4;
    int v[4]; int s = 0;
#pragma unroll
    for (int j = 0; j < 4; j++) {
      v[j] = (idx0 + j < N_NODES) ? deg[idx0 + j] : 0;
      s += v[j];
    }
    sdata[tid] = s;
    __syncthreads();
    for (int o = 1; o < 256; o <<= 1) {
      int x = (tid >= o) ? sdata[tid - o] : 0;
      __syncthreads();
      sdata[tid] += x;
      __syncthreads();
    }
    int excl = sdata[tid] - s + carry;
    int total = sdata[255];
    int run = excl;
#pragma unroll
    for (int j = 0; j < 4; j++) {
      run += v[j];
      if (idx0 + j < N_NODES) off[idx0 + j + 1] = run;
    }
    carry += total;
    __syncthreads();
  }
}

__global__ void scatter_kernel(const int* __restrict__ ei, int* __restrict__ cursor,
                               int* __restrict__ csr_src) {
  int e = blockIdx.x * blockDim.x + threadIdx.x;
  if (e < N_EDGES) {
    int d = ei[N_EDGES + e];
    int p = atomicAdd(&cursor[d], 1);
    csr_src[p] = ei[e];
  }
}

// ---------------- packers ----------------
__global__ void convert_x(const float* __restrict__ x, unsigned short* __restrict__ xp) {
  int t = blockIdx.x * blockDim.x + threadIdx.x;
  const int npc = K0PAD / 8;
  if (t >= M_PAD * npc) return;
  int r = t / npc, g = t % npc;
  int kt = g >> 2, kb = g & 3;
  int k0 = kt * 32 + kb * 8;
  us8 hv, lv;
#pragma unroll
  for (int j = 0; j < 8; j++) {
    int k = k0 + j;
    float v = (r < N_NODES && k < IN_DIM) ? x[(long)r * IN_DIM + k] : 0.0f;
    unsigned short h, l; bsplit(v, h, l);
    hv[j] = h; lv[j] = l;
  }
  char* base = (char*)xp + (size_t)r * (4 * K0PAD) + kt * 128;
  int x7 = r & 7;
  *(us8*)(base + (((2 * kb) ^ x7) << 4)) = hv;
  *(us8*)(base + (((2 * kb + 1) ^ x7) << 4)) = lv;
}

__global__ void convert_W0(const float* __restrict__ W, unsigned short* __restrict__ Wt) {
  int t = blockIdx.x * blockDim.x + threadIdx.x;
  const int npc = K0PAD >> 3;
  if (t >= F_HID * npc) return;
  int n = t / npc, g = t % npc;
  int kt = g >> 2, kb = g & 3;
  int k0 = kt * 32 + kb * 8;
  us8 hv, lv;
#pragma unroll
  for (int j = 0; j < 8; j++) {
    int k = k0 + j;
    float v = (k < IN_DIM) ? W[(long)k * F_HID + n] : 0.0f;
    unsigned short h, l; bsplit(v, h, l);
    hv[j] = h; lv[j] = l;
  }
  char* base = (char*)Wt + (size_t)n * (4 * K0PAD) + kt * 128;
  int x7 = n & 7;
  *(us8*)(base + (((2 * kb) ^ x7) << 4)) = hv;
  *(us8*)(base + (((2 * kb + 1) ^ x7) << 4)) = lv;
}

__global__ void convert_W123(const float* __restrict__ W1, const float* __restrict__ W2,
                             const float* __restrict__ W3, unsigned short* __restrict__ Wt1,
                             unsigned short* __restrict__ Wt2, unsigned short* __restrict__ Wt3) {
  int t = blockIdx.x * blockDim.x + threadIdx.x;
  const int npc = F_HID >> 3;
  if (t >= F_HID * npc) return;
  const float* W = blockIdx.y == 0 ? W1 : (blockIdx.y == 1 ? W2 : W3);
  unsigned short* Wt = blockIdx.y == 0 ? Wt1 : (blockIdx.y == 1 ? Wt2 : Wt3);
  int n = t / npc, g = t % npc;
  int kt = g >> 2, kb = g & 3;
  int k0 = kt * 32 + kb * 8;
  us8 hv, lv;
#pragma unroll
  for (int j = 0; j < 8; j++) {
    int k = k0 + j;
    float v = W[(long)k * F_HID + n];
    unsigned short h, l; bsplit(v, h, l);
    hv[j] = h; lv[j] = l;
  }
  char* base = (char*)Wt + (size_t)n * (4 * F_HID) + kt * 128;
  int x7 = n & 7;
  *(us8*)(base + (((2 * kb) ^ x7) << 4)) = hv;
  *(us8*)(base + (((2 * kb + 1) ^ x7) << 4)) = lv;
}

// ---------------- split-bf16 MFMA GEMM + fused attention dots ----------------
template <int K>
__global__ __launch_bounds__(256) void gemm_mfma(const unsigned short* __restrict__ Ap,
                                                 const unsigned short* __restrict__ Bp,
                                                 const float* __restrict__ AS,
                                                 const float* __restrict__ AD,
                                                 float* __restrict__ als,
                                                 float* __restrict__ ald,
                                                 _Float16* __restrict__ O) {
  constexpr int NKT = K / 32;
  constexpr size_t RB = 4 * K;
  __shared__ __align__(16) char smA[16384];
  __shared__ __align__(16) char smB[16384];
  int xcd = blockIdx.x & 7, slot = blockIdx.x >> 3;
  int bn = slot % 3, tt = slot / 3;
  int bm = tt * 8 + xcd;
  if (bm >= NBM) return;
  int row0 = bm * 128, col0 = bn * 128;
  int tid = threadIdx.x, lane = tid & 63, wv = tid >> 6;
  int wy = wv >> 1, wx = wv & 1;

  f32x4 acc[4][4];
#pragma unroll
  for (int i = 0; i < 4; i++)
#pragma unroll
    for (int j = 0; j < 4; j++) acc[i][j] = (f32x4)0.0f;

  const char* Ab = (const char*)Ap + (size_t)row0 * RB;
  const char* Bb = (const char*)Bp + (size_t)col0 * RB;

  int kb2 = (lane >> 4) * 2;
  int x7 = lane & 7;
  int rA = wy * 64 + (lane & 15);
  int rB = wx * 64 + (lane & 15);

  for (int kt = 0; kt < NKT; ++kt) {
#pragma unroll
    for (int i = 0; i < 4; ++i) {
      int b = wv * 4096 + i * 1024;
      int bl = b + lane * 16;
      int r = bl >> 7, q = bl & 127;
      gload16(Ab + (size_t)r * RB + kt * 128 + q, smA + b);
      gload16(Bb + (size_t)r * RB + kt * 128 + q, smB + b);
    }
    __syncthreads();

    bf16x8 ah[4], alo[4], bh[4], blo[4];
#pragma unroll
    for (int mf = 0; mf < 4; ++mf) {
      const char* p = smA + (rA + mf * 16) * 128;
      ah[mf]  = *(const bf16x8*)(p + ((kb2 ^ x7) << 4));
      alo[mf] = *(const bf16x8*)(p + (((kb2 + 1) ^ x7) << 4));
    }
#pragma unroll
    for (int nf = 0; nf < 4; ++nf) {
      const char* p = smB + (rB + nf * 16) * 128;
      bh[nf]  = *(const bf16x8*)(p + ((kb2 ^ x7) << 4));
      blo[nf] = *(const bf16x8*)(p + (((kb2 + 1) ^ x7) << 4));
    }
#pragma unroll
    for (int mf = 0; mf < 4; ++mf)
#pragma unroll
      for (int nf = 0; nf < 4; ++nf) {
        acc[mf][nf] = __builtin_amdgcn_mfma_f32_16x16x32_bf16(ah[mf], bh[nf], acc[mf][nf], 0, 0, 0);
        acc[mf][nf] = __builtin_amdgcn_mfma_f32_16x16x32_bf16(alo[mf], bh[nf], acc[mf][nf], 0, 0, 0);
        acc[mf][nf] = __builtin_amdgcn_mfma_f32_16x16x32_bf16(ah[mf], blo[nf], acc[mf][nf], 0, 0, 0);
      }
    __syncthreads();
  }

  int cr = (lane >> 4) * 4, cc = lane & 15;
#pragma unroll
  for (int mf = 0; mf < 4; ++mf)
#pragma unroll
    for (int r = 0; r < 4; ++r) {
      int row = row0 + wy * 64 + mf * 16 + cr + r;
      if (row < N_NODES) {
#pragma unroll
        for (int nf = 0; nf < 4; ++nf)
          O[(size_t)row * F_HID + col0 + wx * 64 + nf * 16 + cc] = (_Float16)acc[mf][nf][r];
      }
    }
  // fused dots: head = 2*bn + wx
  int head = bn * 2 + wx;
  float sa[4], da[4];
#pragma unroll
  for (int nf = 0; nf < 4; ++nf) {
    sa[nf] = AS[head * CH + nf * 16 + cc];
    da[nf] = AD[head * CH + nf * 16 + cc];
  }
#pragma unroll
  for (int mf = 0; mf < 4; ++mf)
#pragma unroll
    for (int r = 0; r < 4; ++r) {
      float ps = 0.0f, pd = 0.0f;
#pragma unroll
      for (int nf = 0; nf < 4; ++nf) {
        ps += acc[mf][nf][r] * sa[nf];
        pd += acc[mf][nf][r] * da[nf];
      }
#pragma unroll
      for (int o = 1; o < 16; o <<= 1) {
        ps += __shfl_xor(ps, o);
        pd += __shfl_xor(pd, o);
      }
      int row = row0 + wy * 64 + mf * 16 + cr + r;
      if (cc == 0 && row < N_NODES) {
        als[row * HEADS + head] = ps;
        ald[row * HEADS + head] = pd;
      }
    }
}

// ---------------- phase-split agg core: 8 nodes x 48 threads x 8 channels ----------
// Fast path (dmax <= CAP, ~always): A) logits -> LDS; barrier; B) parallel softmax
// (48 pairs x 8 lanes); barrier; C) f16x8 gather, NO trailing barrier (each thread
// independent through epilogue -> degree imbalance costs nothing block-wide).
// Slow chunked path retained for correctness.
#define AGG_CORE8(FEAT, OFF, CSR, ALS, ALD)                                       \
  int tid = threadIdx.x;                                                          \
  int sub = tid / 48, t48 = tid - sub * 48;                                       \
  int nb = blockIdx.x * 8;                                                        \
  int n = nb + sub;                                                               \
  int c8 = t48 * 8, h = t48 >> 3;                                                 \
  int o_[9];                                                                      \
  _Pragma("unroll")                                                               \
  for (int k = 0; k < 9; ++k) o_[k] = OFF[nb + k];                                \
  int dmax = 0;                                                                   \
  _Pragma("unroll")                                                               \
  for (int k = 0; k < 8; ++k) dmax = max(dmax, o_[k + 1] - o_[k]);                \
  int s0 = o_[sub], deg = o_[sub + 1] - o_[sub];                                  \
  int pr = tid >> 3, pl = tid & 7;                                                \
  int psub = pr / 6, ph = pr - psub * 6;                                          \
  int ps0 = o_[psub], pdeg = o_[psub + 1] - o_[psub];                             \
  float a0 = 0, a1 = 0, a2 = 0, a3 = 0, a4 = 0, a5 = 0, a6 = 0, a7 = 0;           \
  if (dmax <= CAP) {                                                              \
    for (int j = t48; j < deg; j += 48) lsrc[sub][j] = CSR[s0 + j];               \
    for (int j = t48; j < deg * 6; j += 48) {                                     \
      int i = j / 6, hh = j - i * 6;                                              \
      int s = CSR[s0 + i];                                                        \
      float e = ALS[s * 6 + hh] + ALD[n * 6 + hh];                                \
      e = e > 0.0f ? e : 0.2f * e;                                                \
      lew[sub][hh][i] = e;                                                        \
    }                                                                             \
    __syncthreads();                                                              \
    if (pdeg > 0) {                                                               \
      float mc = -INFINITY;                                                       \
      for (int i = pl; i < pdeg; i += 8) mc = fmaxf(mc, lew[psub][ph][i]);        \
      mc = fmaxf(mc, __shfl_xor(mc, 1));                                          \
      mc = fmaxf(mc, __shfl_xor(mc, 2));                                          \
      mc = fmaxf(mc, __shfl_xor(mc, 4));                                          \
      float scp = 0.0f;                                                           \
      for (int i = pl; i < pdeg; i += 8) {                                        \
        float wv = __expf(lew[psub][ph][i] - mc);                                 \
        lew[psub][ph][i] = wv;                                                    \
        scp += wv;                                                                \
      }                                                                           \
      scp += __shfl_xor(scp, 1);                                                  \
      scp += __shfl_xor(scp, 2);                                                  \
      scp += __shfl_xor(scp, 4);                                                  \
      if (pl == 0) lrr[psub][ph] = 1.0f / (scp + 1e-16f);                         \
    } else if (pl == 0) lrr[psub][ph] = 0.0f;                                     \
    __syncthreads();                                                              \
    for (int i = 0; i < deg; ++i) {                                               \
      int s = lsrc[sub][i];                                                       \
      float wv = lew[sub][h][i];                                                  \
      f16x8 fv = *(const f16x8*)(FEAT + (size_t)s * F_HID + c8);                  \
      a0 += wv * (float)fv[0]; a1 += wv * (float)fv[1];                           \
      a2 += wv * (float)fv[2]; a3 += wv * (float)fv[3];                           \
      a4 += wv * (float)fv[4]; a5 += wv * (float)fv[5];                           \
      a6 += wv * (float)fv[6]; a7 += wv * (float)fv[7];                           \
    }                                                                             \
    float rr = lrr[sub][h];                                                       \
    a0 *= rr; a1 *= rr; a2 *= rr; a3 *= rr;                                       \
    a4 *= rr; a5 *= rr; a6 *= rr; a7 *= rr;                                       \
  } else {                                                                        \
    float m_run = -INFINITY, s_run = 0.0f;                                        \
    int nch = (dmax + CAP - 1) / CAP;                                             \
    for (int ch = 0; ch < nch; ++ch) {                                            \
      int base = ch * CAP;                                                        \
      int cl = deg - base; cl = cl < 0 ? 0 : (cl > CAP ? CAP : cl);               \
      for (int j = t48; j < cl; j += 48) lsrc[sub][j] = CSR[s0 + base + j];       \
      for (int j = t48; j < cl * 6; j += 48) {                                    \
        int i = j / 6, hh = j - i * 6;                                            \
        int s = CSR[s0 + base + i];                                               \
        float e = ALS[s * 6 + hh] + ALD[n * 6 + hh];                              \
        e = e > 0.0f ? e : 0.2f * e;                                              \
        lew[sub][hh][i] = e;                                                      \
      }                                                                           \
      __syncthreads();                                                            \
      int pcl = pdeg - base; pcl = pcl < 0 ? 0 : (pcl > CAP ? CAP : pcl);         \
      float asc = 1.0f;                                                           \
      if (pcl > 0) {                                                              \
        float mc = -INFINITY;                                                     \
        for (int i = pl; i < pcl; i += 8) mc = fmaxf(mc, lew[psub][ph][i]);       \
        mc = fmaxf(mc, __shfl_xor(mc, 1));                                        \
        mc = fmaxf(mc, __shfl_xor(mc, 2));                                        \
        mc = fmaxf(mc, __shfl_xor(mc, 4));                                        \
        float mn = fmaxf(m_run, mc);                                              \
        asc = (m_run == -INFINITY) ? 0.0f : __expf(m_run - mn);                   \
        float scp = 0.0f;                                                         \
        for (int i = pl; i < pcl; i += 8) {                                       \
          float wv = __expf(lew[psub][ph][i] - mn);                               \
          lew[psub][ph][i] = wv;                                                  \
          scp += wv;                                                              \
        }                                                                         \
        scp += __shfl_xor(scp, 1);                                                \
        scp += __shfl_xor(scp, 2);                                                \
        scp += __shfl_xor(scp, 4);                                                \
        s_run = s_run * asc + scp;                                                \
        m_run = mn;                                                               \
      }                                                                           \
      if (pl == 0) {                                                              \
        lasc[psub][ph] = asc;                                                     \
        lrr[psub][ph] = (pdeg > 0) ? 1.0f / (s_run + 1e-16f) : 0.0f;              \
      }                                                                           \
      __syncthreads();                                                            \
      float c0 = 0, c1 = 0, c2 = 0, c3 = 0, c4_ = 0, c5 = 0, c6 = 0, c7 = 0;      \
      for (int i = 0; i < cl; ++i) {                                              \
        int s = lsrc[sub][i];                                                     \
        float wv = lew[sub][h][i];                                                \
        f16x8 fv = *(const f16x8*)(FEAT + (size_t)s * F_HID + c8);                \
        c0 += wv * (float)fv[0]; c1 += wv * (float)fv[1];                         \
        c2 += wv * (float)fv[2]; c3 += wv * (float)fv[3];                         \
        c4_ += wv * (float)fv[4]; c5 += wv * (float)fv[5];                        \
        c6 += wv * (float)fv[6]; c7 += wv * (float)fv[7];                         \
      }                                                                           \
      float asc2 = lasc[sub][h];                                                  \
      a0 = a0 * asc2 + c0; a1 = a1 * asc2 + c1;                                   \
      a2 = a2 * asc2 + c2; a3 = a3 * asc2 + c3;                                   \
      a4 = a4 * asc2 + c4_; a5 = a5 * asc2 + c5;                                  \
      a6 = a6 * asc2 + c6; a7 = a7 * asc2 + c7;                                   \
      __syncthreads();                                                            \
    }                                                                             \
    float rr = lrr[sub][h];                                                       \
    a0 *= rr; a1 *= rr; a2 *= rr; a3 *= rr;                                       \
    a4 *= rr; a5 *= rr; a6 *= rr; a7 *= rr;                                       \
  }                                                                               \
  (void)ps0;

// hidden layers: normalize + bias + ELU + split-bf16 pack (per-thread, no sync)
__global__ __launch_bounds__(384) void agg_hidden(const _Float16* __restrict__ feat,
                                                  const int* __restrict__ off,
                                                  const int* __restrict__ csr_src,
                                                  const float* __restrict__ al_s,
                                                  const float* __restrict__ al_d,
                                                  const float* __restrict__ bias,
                                                  unsigned short* __restrict__ Apk) {
  __shared__ int   lsrc[8][CAP];
  __shared__ float lew[8][6][CAP + 1];
  __shared__ float lasc[8][6];
  __shared__ float lrr[8][6];
  AGG_CORE8(feat, off, csr_src, al_s, al_d)
  float v[8] = {a0, a1, a2, a3, a4, a5, a6, a7};
  us8 hv, lv;
#pragma unroll
  for (int j = 0; j < 8; ++j) {
    float t = v[j] + bias[c8 + j];
    t = t > 0.0f ? t : (__expf(t) - 1.0f);
    unsigned short hh2, ll2;
    bsplit(t, hh2, ll2);
    hv[j] = hh2; lv[j] = ll2;
  }
  int kt = c8 >> 5, kb = (c8 >> 3) & 3;
  char* basep = (char*)Apk + (size_t)n * (4 * F_HID) + kt * 128;
  int x7 = n & 7;
  *(us8*)(basep + (((2 * kb) ^ x7) << 4)) = hv;
  *(us8*)(basep + (((2 * kb + 1) ^ x7) << 4)) = lv;
}

// output layer: normalize + head-mean + bias
__global__ __launch_bounds__(384) void agg_out(const _Float16* __restrict__ feat,
                                               const int* __restrict__ off,
                                               const int* __restrict__ csr_src,
                                               const float* __restrict__ al_s,
                                               const float* __restrict__ al_d,
                                               const float* __restrict__ b3,
                                               float* __restrict__ out) {
  __shared__ int   lsrc[8][CAP];
  __shared__ float lew[8][6][CAP + 1];
  __shared__ float lasc[8][6];
  __shared__ float lrr[8][6];
  __shared__ float red[8][F_HID];
  AGG_CORE8(feat, off, csr_src, al_s, al_d)
  red[sub][c8 + 0] = a0; red[sub][c8 + 1] = a1;
  red[sub][c8 + 2] = a2; red[sub][c8 + 3] = a3;
  red[sub][c8 + 4] = a4; red[sub][c8 + 5] = a5;
  red[sub][c8 + 6] = a6; red[sub][c8 + 7] = a7;
  __syncthreads();
  if (t48 < 8) {
    int c = t48 * 8;
    float o[8] = {0, 0, 0, 0, 0, 0, 0, 0};
#pragma unroll
    for (int hh = 0; hh < HEADS; hh++)
#pragma unroll
      for (int j = 0; j < 8; j++) o[j] += red[sub][hh * CH + c + j];
    f32x4 o0, o1;
#pragma unroll
    for (int j = 0; j < 4; j++) {
      o0[j] = o[j] * (1.0f / 6.0f) + b3[c + j];
      o1[j] = o[j + 4] * (1.0f / 6.0f) + b3[c + j + 4];
    }
    *(f32x4*)(out + (size_t)n * CH + c) = o0;
    *(f32x4*)(out + (size_t)n * CH + c + 4) = o1;
  }
}

extern "C" void kernel_launch(void* const* d_in, const int* in_sizes, int n_in,
                              void* d_out, int out_size, void* d_ws, size_t ws_size,
                              hipStream_t stream) {
  const float* x  = (const float*)d_in[0];
  const int*   ei = (const int*)d_in[1];
  const float* W_[4]  = {(const float*)d_in[2], (const float*)d_in[6],
                         (const float*)d_in[10], (const float*)d_in[14]};
  const float* AS_[4] = {(const float*)d_in[3], (const float*)d_in[7],
                         (const float*)d_in[11], (const float*)d_in[15]};
  const float* AD_[4] = {(const float*)d_in[4], (const float*)d_in[8],
                         (const float*)d_in[12], (const float*)d_in[16]};
  const float* B_[4]  = {(const float*)d_in[5], (const float*)d_in[9],
                         (const float*)d_in[13], (const float*)d_in[17]};
  float* out = (float*)d_out;

  // ---- workspace layout ----
  char* w = (char*)d_ws;
  _Float16* feat = (_Float16*)w;                  // [N,384] fp16 GEMM out
  w += (size_t)N_NODES * F_HID * 2;
  unsigned short* Apk = (unsigned short*)w;       // packed split-bf16 A (also layer-0 x)
  w += (size_t)M_PAD * 2 * F_HID * 2;
  unsigned short* Wt0 = (unsigned short*)w; w += (size_t)F_HID * 2 * K0PAD * 2;
  unsigned short* Wt1 = (unsigned short*)w; w += (size_t)F_HID * 2 * F_HID * 2;
  unsigned short* Wt2 = (unsigned short*)w; w += (size_t)F_HID * 2 * F_HID * 2;
  unsigned short* Wt3 = (unsigned short*)w; w += (size_t)F_HID * 2 * F_HID * 2;
  float* als = (float*)w; w += (size_t)N_NODES * HEADS * 4;
  float* ald = (float*)w; w += (size_t)N_NODES * HEADS * 4;
  int* off = (int*)w; w += (N_NODES + 1) * 4;
  int* cur = (int*)w; w += N_NODES * 4;
  int* deg = (int*)w; w += N_NODES * 4;
  int* csr = (int*)w;

  // ---- CSR build ----
  (void)hipMemsetAsync(deg, 0, N_NODES * sizeof(int), stream);
  count_kernel<<<cdiv(N_EDGES, 256), 256, 0, stream>>>(ei, deg);
  scan_kernel<<<1, 256, 0, stream>>>(deg, off);
  (void)hipMemcpyAsync(cur, off, N_NODES * sizeof(int), hipMemcpyDeviceToDevice, stream);
  scatter_kernel<<<cdiv(N_EDGES, 256), 256, 0, stream>>>(ei, cur, csr);

  // ---- pack inputs ----
  convert_x<<<cdiv(M_PAD * (K0PAD / 8), 256), 256, 0, stream>>>(x, Apk);
  convert_W0<<<cdiv(F_HID * (K0PAD / 8), 256), 256, 0, stream>>>(W_[0], Wt0);
  {
    dim3 g(cdiv(F_HID * (F_HID / 8), 256), 3);
    convert_W123<<<g, 256, 0, stream>>>(W_[1], W_[2], W_[3], Wt1, Wt2, Wt3);
  }
  (void)hipMemsetAsync((char*)Apk + (size_t)N_NODES * 4 * F_HID, 0,
                       (size_t)(M_PAD - N_NODES) * 4 * F_HID, stream);

  const int gemm_grid = 8 * cdiv(NBM, 8) * 3;  // XCD-grouped
  const int agg_grid = N_NODES / 8;            // 6250

  // ---- Layer 0 (K=160 packed) ----
  gemm_mfma<K0PAD><<<gemm_grid, 256, 0, stream>>>(Apk, Wt0, AS_[0], AD_[0], als, ald, feat);
  agg_hidden<<<agg_grid, 384, 0, stream>>>(feat, off, csr, als, ald, B_[0], Apk);

  // ---- Layers 1,2 (K=384) ----
  gemm_mfma<F_HID><<<gemm_grid, 256, 0, stream>>>(Apk, Wt1, AS_[1], AD_[1], als, ald, feat);
  agg_hidden<<<agg_grid, 384, 0, stream>>>(feat, off, csr, als, ald, B_[1], Apk);

  gemm_mfma<F_HID><<<gemm_grid, 256, 0, stream>>>(Apk, Wt2, AS_[2], AD_[2], als, ald, feat);
  agg_hidden<<<agg_grid, 384, 0, stream>>>(feat, off, csr, als, ald, B_[2], Apk);

  // ---- Layer 3 (K=384, mean over heads) ----
  gemm_mfma<F_HID><<<gemm_grid, 256, 0, stream>>>(Apk, Wt3, AS_[3], AD_[3], als, ald, feat);
  agg_out<<<agg_grid, 384, 0, stream>>>(feat, off, csr, als, ald, B_[3], out);
}

// Round 10
// 661.872 us; speedup vs baseline: 1.2012x; 1.2012x over previous
//
#include <hip/hip_runtime.h>

#define N_NODES 50000
#define M_PAD 50048      // N_NODES rounded up to 128
#define N_EDGES 500000
#define HEADS 6
#define CH 64
#define F_HID 384
#define IN_DIM 131
#define K0PAD 160        // layer-0 K padded to multiple of 32
#define CAP 64           // fast-path max degree
#define NBM 391          // cdiv(N_NODES,128)
#define ATILE3 98304     // (384/32)*8192 bytes per 128-row fp16 A tile
#define ATILE0 40960     // (160/32)*8192
#define BTILE3 196608    // (384/32)*16384 per 128-col split-f16 B tile
#define BTILE0 81920

static inline int cdiv(int a, int b) { return (a + b - 1) / b; }

typedef __attribute__((ext_vector_type(4))) float f32x4;
typedef __attribute__((ext_vector_type(8))) _Float16 f16x8;
typedef __attribute__((ext_vector_type(4))) _Float16 f16x4;

// fp32 -> f16 hi/lo split (for W): v ~= h + l, ~22 effective bits
__device__ __forceinline__ void fsplit(float v, _Float16& h, _Float16& l) {
  h = (_Float16)v;
  l = (_Float16)(v - (float)h);
}

__device__ __forceinline__ void gload16(const void* g, void* lds) {
  __builtin_amdgcn_global_load_lds((const __attribute__((address_space(1))) void*)g,
                                   (__attribute__((address_space(3))) void*)lds, 16, 0, 0);
}

// ---------------- CSR build ----------------
__global__ void count_kernel(const int* __restrict__ ei, int* __restrict__ deg) {
  int e = blockIdx.x * blockDim.x + threadIdx.x;
  if (e < N_EDGES) atomicAdd(&deg[ei[N_EDGES + e]], 1);
}

__global__ void scan_kernel(const int* __restrict__ deg, int* __restrict__ off) {
  __shared__ int sdata[256];
  int tid = threadIdx.x;
  int carry = 0;
  if (tid == 0) off[0] = 0;
  for (int base = 0; base < N_NODES; base += 1024) {
    int idx0 = base + tid * 4;
    int v[4]; int s = 0;
#pragma unroll
    for (int j = 0; j < 4; j++) {
      v[j] = (idx0 + j < N_NODES) ? deg[idx0 + j] : 0;
      s += v[j];
    }
    sdata[tid] = s;
    __syncthreads();
    for (int o = 1; o < 256; o <<= 1) {
      int x = (tid >= o) ? sdata[tid - o] : 0;
      __syncthreads();
      sdata[tid] += x;
      __syncthreads();
    }
    int excl = sdata[tid] - s + carry;
    int total = sdata[255];
    int run = excl;
#pragma unroll
    for (int j = 0; j < 4; j++) {
      run += v[j];
      if (idx0 + j < N_NODES) off[idx0 + j + 1] = run;
    }
    carry += total;
    __syncthreads();
  }
}

__global__ void scatter_kernel(const int* __restrict__ ei, int* __restrict__ cursor,
                               int* __restrict__ csr_src) {
  int e = blockIdx.x * blockDim.x + threadIdx.x;
  if (e < N_EDGES) {
    int d = ei[N_EDGES + e];
    int p = atomicAdd(&cursor[d], 1);
    csr_src[p] = ei[e];
  }
}

// ---------------- packers (chunk-major layout) ----------------
// A plane: [tile=r>>7][kt][kb][r&127] 16B chunks (8 fp16 = k's kt*32+kb*8 .. +7).
__global__ void convert_x(const float* __restrict__ x, char* __restrict__ Apk) {
  int t = blockIdx.x * blockDim.x + threadIdx.x;
  const int npc = K0PAD / 8;  // 20
  if (t >= M_PAD * npc) return;
  int r = t / npc, g = t % npc;
  int kt = g >> 2, kb = g & 3;
  int k0 = kt * 32 + kb * 8;
  f16x8 hv;
#pragma unroll
  for (int j = 0; j < 8; j++) {
    int k = k0 + j;
    float v = (r < N_NODES && k < IN_DIM) ? x[(long)r * IN_DIM + k] : 0.0f;
    hv[j] = (_Float16)v;
  }
  *(f16x8*)(Apk + (size_t)(r >> 7) * ATILE0 + kt * 8192 + kb * 2048 + (r & 127) * 16) = hv;
}

// zero the pad rows (50000..50047) of the K=384 A plane once per call
__global__ void zero_padA(char* __restrict__ Apk) {
  int t = blockIdx.x * blockDim.x + threadIdx.x;
  if (t >= 48 * 48) return;
  int chunk = t / 48, r = 80 + t % 48;
  int kt = chunk >> 2, kb = chunk & 3;
  *(f32x4*)(Apk + (size_t)390 * ATILE3 + kt * 8192 + kb * 2048 + r * 16) = (f32x4)0.0f;
}

// B plane (W^T split f16): [bn=n>>7][kt][s hi/lo][kb][col=n&127] 16B chunks.
__global__ void convert_W0(const float* __restrict__ W, char* __restrict__ Wt) {
  int t = blockIdx.x * blockDim.x + threadIdx.x;
  const int npc = K0PAD >> 3;
  if (t >= F_HID * npc) return;
  int n = t / npc, g = t % npc;
  int kt = g >> 2, kb = g & 3;
  int k0 = kt * 32 + kb * 8;
  f16x8 hv, lv;
#pragma unroll
  for (int j = 0; j < 8; j++) {
    int k = k0 + j;
    float v = (k < IN_DIM) ? W[(long)k * F_HID + n] : 0.0f;
    _Float16 h, l; fsplit(v, h, l);
    hv[j] = h; lv[j] = l;
  }
  char* base = Wt + (size_t)(n >> 7) * BTILE0 + kt * 16384 + kb * 2048 + (n & 127) * 16;
  *(f16x8*)base = hv;
  *(f16x8*)(base + 8192) = lv;
}

__global__ void convert_W123(const float* __restrict__ W1, const float* __restrict__ W2,
                             const float* __restrict__ W3, char* __restrict__ Wt1,
                             char* __restrict__ Wt2, char* __restrict__ Wt3) {
  int t = blockIdx.x * blockDim.x + threadIdx.x;
  const int npc = F_HID >> 3;
  if (t >= F_HID * npc) return;
  const float* W = blockIdx.y == 0 ? W1 : (blockIdx.y == 1 ? W2 : W3);
  char* Wt = blockIdx.y == 0 ? Wt1 : (blockIdx.y == 1 ? Wt2 : Wt3);
  int n = t / npc, g = t % npc;
  int kt = g >> 2, kb = g & 3;
  int k0 = kt * 32 + kb * 8;
  f16x8 hv, lv;
#pragma unroll
  for (int j = 0; j < 8; j++) {
    float v = W[(long)(k0 + j) * F_HID + n];
    _Float16 h, l; fsplit(v, h, l);
    hv[j] = h; lv[j] = l;
  }
  char* base = Wt + (size_t)(n >> 7) * BTILE3 + kt * 16384 + kb * 2048 + (n & 127) * 16;
  *(f16x8*)base = hv;
  *(f16x8*)(base + 8192) = lv;
}

// ---------------- fp16-A x split-f16-W MFMA GEMM + fused attention dots ----------
template <int K>
__global__ __launch_bounds__(256) void gemm_mfma(const char* __restrict__ Ap,
                                                 const char* __restrict__ Bp,
                                                 const float* __restrict__ AS,
                                                 const float* __restrict__ AD,
                                                 float* __restrict__ als,
                                                 float* __restrict__ ald,
                                                 _Float16* __restrict__ O) {
  constexpr int NKT = K / 32;
  __shared__ __align__(16) char smA[8192];
  __shared__ __align__(16) char smB[16384];
  int xcd = blockIdx.x & 7, slot = blockIdx.x >> 3;
  int bn = slot % 3, tt = slot / 3;
  int bm = tt * 8 + xcd;
  if (bm >= NBM) return;
  int row0 = bm * 128, col0 = bn * 128;
  int tid = threadIdx.x, lane = tid & 63, wv = tid >> 6;
  int wy = wv >> 1, wx = wv & 1;

  f32x4 acc[4][4];
#pragma unroll
  for (int i = 0; i < 4; i++)
#pragma unroll
    for (int j = 0; j < 4; j++) acc[i][j] = (f32x4)0.0f;

  const char* Ab = Ap + (size_t)bm * (NKT * 8192);
  const char* Bb = Bp + (size_t)bn * (NKT * 16384);
  int rsel = lane & 15, ksel = lane >> 4;

  for (int kt = 0; kt < NKT; ++kt) {
    // stage 8KB A + 16KB B, linear (chunk-major layout => conflict-free ds_read)
#pragma unroll
    for (int i = 0; i < 2; ++i) {
      int b = (i * 4 + wv) * 1024;
      gload16(Ab + (size_t)kt * 8192 + b + lane * 16, smA + b);
    }
#pragma unroll
    for (int i = 0; i < 4; ++i) {
      int b = (i * 4 + wv) * 1024;
      gload16(Bb + (size_t)kt * 16384 + b + lane * 16, smB + b);
    }
    __syncthreads();

    f16x8 av[4], bh[4], bl[4];
#pragma unroll
    for (int mf = 0; mf < 4; ++mf)
      av[mf] = *(const f16x8*)(smA + ksel * 2048 + (wy * 64 + mf * 16 + rsel) * 16);
#pragma unroll
    for (int nf = 0; nf < 4; ++nf) {
      int o = ksel * 2048 + (wx * 64 + nf * 16 + rsel) * 16;
      bh[nf] = *(const f16x8*)(smB + o);
      bl[nf] = *(const f16x8*)(smB + 8192 + o);
    }
#pragma unroll
    for (int mf = 0; mf < 4; ++mf)
#pragma unroll
      for (int nf = 0; nf < 4; ++nf) {
        acc[mf][nf] = __builtin_amdgcn_mfma_f32_16x16x32_f16(av[mf], bh[nf], acc[mf][nf], 0, 0, 0);
        acc[mf][nf] = __builtin_amdgcn_mfma_f32_16x16x32_f16(av[mf], bl[nf], acc[mf][nf], 0, 0, 0);
      }
    __syncthreads();
  }

  int cr = (lane >> 4) * 4, cc = lane & 15;
#pragma unroll
  for (int mf = 0; mf < 4; ++mf)
#pragma unroll
    for (int r = 0; r < 4; ++r) {
      int row = row0 + wy * 64 + mf * 16 + cr + r;
      if (row < N_NODES) {
#pragma unroll
        for (int nf = 0; nf < 4; ++nf)
          O[(size_t)row * F_HID + col0 + wx * 64 + nf * 16 + cc] = (_Float16)acc[mf][nf][r];
      }
    }
  // fused dots: head = 2*bn + wx; this wave holds its full 64 cols
  int head = bn * 2 + wx;
  float sa[4], da[4];
#pragma unroll
  for (int nf = 0; nf < 4; ++nf) {
    sa[nf] = AS[head * CH + nf * 16 + cc];
    da[nf] = AD[head * CH + nf * 16 + cc];
  }
#pragma unroll
  for (int mf = 0; mf < 4; ++mf)
#pragma unroll
    for (int r = 0; r < 4; ++r) {
      float ps = 0.0f, pd = 0.0f;
#pragma unroll
      for (int nf = 0; nf < 4; ++nf) {
        ps += acc[mf][nf][r] * sa[nf];
        pd += acc[mf][nf][r] * da[nf];
      }
#pragma unroll
      for (int o = 1; o < 16; o <<= 1) {
        ps += __shfl_xor(ps, o);
        pd += __shfl_xor(pd, o);
      }
      int row = row0 + wy * 64 + mf * 16 + cr + r;
      if (cc == 0 && row < N_NODES) {
        als[row * HEADS + head] = ps;
        ald[row * HEADS + head] = pd;
      }
    }
}

// ---------------- phase-split agg core (R8-proven: 4 nodes x 96 thr) ----------
typedef __attribute__((ext_vector_type(4))) _Float16 f16x4t;
#define AGG_CORE(FEAT, OFF, CSR, ALS, ALD)                                        \
  int tid = threadIdx.x;                                                          \
  int sub = tid / 96, t96 = tid - sub * 96;                                       \
  int nb = blockIdx.x * 4;                                                        \
  int n = nb + sub;                                                               \
  int c4 = t96 * 4, h = t96 >> 4;                                                 \
  int o_[5];                                                                      \
  _Pragma("unroll")                                                               \
  for (int k = 0; k < 5; ++k) o_[k] = OFF[nb + k];                                \
  int dmax = 0;                                                                   \
  _Pragma("unroll")                                                               \
  for (int k = 0; k < 4; ++k) dmax = max(dmax, o_[k + 1] - o_[k]);                \
  int nch = (dmax + CAP - 1) / CAP; if (nch < 1) nch = 1;                         \
  int s0 = o_[sub], deg = o_[sub + 1] - o_[sub];                                  \
  int pr = tid >> 4, pl = tid & 15;                                               \
  int psub = pr / 6, ph = pr - psub * 6;                                          \
  int pdeg = o_[psub + 1] - o_[psub];                                             \
  float m_run = -INFINITY, s_run = 0.0f;                                          \
  float a0 = 0, a1 = 0, a2 = 0, a3 = 0;                                           \
  for (int ch = 0; ch < nch; ++ch) {                                              \
    int base = ch * CAP;                                                          \
    int cl = deg - base; cl = cl < 0 ? 0 : (cl > CAP ? CAP : cl);                 \
    if (t96 < cl) lsrc[sub][t96] = CSR[s0 + base + t96];                          \
    for (int j = t96; j < cl * 6; j += 96) {                                      \
      int i = j / 6, hh = j - i * 6;                                              \
      int s = CSR[s0 + base + i];                                                 \
      float e = ALS[s * 6 + hh] + ALD[n * 6 + hh];                                \
      e = e > 0.0f ? e : 0.2f * e;                                                \
      lew[sub][hh][i] = e;                                                        \
    }                                                                             \
    __syncthreads();                                                              \
    int pcl = pdeg - base; pcl = pcl < 0 ? 0 : (pcl > CAP ? CAP : pcl);           \
    float asc = 1.0f;                                                             \
    if (pcl > 0) {                                                                \
      float mc = -INFINITY;                                                       \
      for (int i = pl; i < pcl; i += 16) mc = fmaxf(mc, lew[psub][ph][i]);        \
      mc = fmaxf(mc, __shfl_xor(mc, 1));                                          \
      mc = fmaxf(mc, __shfl_xor(mc, 2));                                          \
      mc = fmaxf(mc, __shfl_xor(mc, 4));                                          \
      mc = fmaxf(mc, __shfl_xor(mc, 8));                                          \
      float mn = fmaxf(m_run, mc);                                                \
      asc = (m_run == -INFINITY) ? 0.0f : __expf(m_run - mn);                     \
      float scp = 0.0f;                                                           \
      for (int i = pl; i < pcl; i += 16) {                                        \
        float wv = __expf(lew[psub][ph][i] - mn);                                 \
        lew[psub][ph][i] = wv;                                                    \
        scp += wv;                                                                \
      }                                                                           \
      scp += __shfl_xor(scp, 1);                                                  \
      scp += __shfl_xor(scp, 2);                                                  \
      scp += __shfl_xor(scp, 4);                                                  \
      scp += __shfl_xor(scp, 8);                                                  \
      s_run = s_run * asc + scp;                                                  \
      m_run = mn;                                                                 \
    }                                                                             \
    if (pl == 0) {                                                                \
      lasc[psub][ph] = asc;                                                       \
      if (ch == nch - 1) lrr[psub][ph] = 1.0f / (s_run + 1e-16f);                 \
    }                                                                             \
    __syncthreads();                                                              \
    float cc0 = 0, cc1 = 0, cc2 = 0, cc3 = 0;                                     \
    int i = 0;                                                                    \
    for (; i + 4 <= cl; i += 4) {                                                 \
      int sA = lsrc[sub][i], sB = lsrc[sub][i + 1];                               \
      int sC = lsrc[sub][i + 2], sD = lsrc[sub][i + 3];                           \
      float wA = lew[sub][h][i], wB = lew[sub][h][i + 1];                         \
      float wC = lew[sub][h][i + 2], wD = lew[sub][h][i + 3];                     \
      f16x4t fA = *(const f16x4t*)(FEAT + (size_t)sA * F_HID + c4);               \
      f16x4t fB = *(const f16x4t*)(FEAT + (size_t)sB * F_HID + c4);               \
      f16x4t fC = *(const f16x4t*)(FEAT + (size_t)sC * F_HID + c4);               \
      f16x4t fD = *(const f16x4t*)(FEAT + (size_t)sD * F_HID + c4);               \
      cc0 += wA * (float)fA[0]; cc1 += wA * (float)fA[1];                         \
      cc2 += wA * (float)fA[2]; cc3 += wA * (float)fA[3];                         \
      cc0 += wB * (float)fB[0]; cc1 += wB * (float)fB[1];                         \
      cc2 += wB * (float)fB[2]; cc3 += wB * (float)fB[3];                         \
      cc0 += wC * (float)fC[0]; cc1 += wC * (float)fC[1];                         \
      cc2 += wC * (float)fC[2]; cc3 += wC * (float)fC[3];                         \
      cc0 += wD * (float)fD[0]; cc1 += wD * (float)fD[1];                         \
      cc2 += wD * (float)fD[2]; cc3 += wD * (float)fD[3];                         \
    }                                                                             \
    for (; i < cl; ++i) {                                                         \
      int s = lsrc[sub][i];                                                       \
      float wv = lew[sub][h][i];                                                  \
      f16x4t fv = *(const f16x4t*)(FEAT + (size_t)s * F_HID + c4);                \
      cc0 += wv * (float)fv[0]; cc1 += wv * (float)fv[1];                         \
      cc2 += wv * (float)fv[2]; cc3 += wv * (float)fv[3];                         \
    }                                                                             \
    float asc2 = lasc[sub][h];                                                    \
    a0 = a0 * asc2 + cc0; a1 = a1 * asc2 + cc1;                                   \
    a2 = a2 * asc2 + cc2; a3 = a3 * asc2 + cc3;                                   \
    __syncthreads();                                                              \
  }                                                                               \
  float rr = lrr[sub][h];

// hidden layers: normalize + bias + ELU + fp16 pack (chunk-major A plane)
__global__ __launch_bounds__(384) void agg_hidden(const _Float16* __restrict__ feat,
                                                  const int* __restrict__ off,
                                                  const int* __restrict__ csr_src,
                                                  const float* __restrict__ al_s,
                                                  const float* __restrict__ al_d,
                                                  const float* __restrict__ bias,
                                                  char* __restrict__ Apk) {
  __shared__ int   lsrc[4][CAP + 1];
  __shared__ float lew[4][6][CAP + 1];
  __shared__ float lasc[4][6];
  __shared__ float lrr[4][6];
  AGG_CORE(feat, off, csr_src, al_s, al_d)
  float v0 = a0 * rr + bias[c4 + 0];
  float v1 = a1 * rr + bias[c4 + 1];
  float v2 = a2 * rr + bias[c4 + 2];
  float v3 = a3 * rr + bias[c4 + 3];
  v0 = v0 > 0.0f ? v0 : (__expf(v0) - 1.0f);
  v1 = v1 > 0.0f ? v1 : (__expf(v1) - 1.0f);
  v2 = v2 > 0.0f ? v2 : (__expf(v2) - 1.0f);
  v3 = v3 > 0.0f ? v3 : (__expf(v3) - 1.0f);
  f16x4 pv;
  pv[0] = (_Float16)v0; pv[1] = (_Float16)v1;
  pv[2] = (_Float16)v2; pv[3] = (_Float16)v3;
  int kt = c4 >> 5, kb = (c4 >> 3) & 3, j = c4 & 7;
  *(f16x4*)(Apk + (size_t)(n >> 7) * ATILE3 + kt * 8192 + kb * 2048 +
            (n & 127) * 16 + j * 2) = pv;
}

// output layer: normalize + head-mean + bias
__global__ __launch_bounds__(384) void agg_out(const _Float16* __restrict__ feat,
                                               const int* __restrict__ off,
                                               const int* __restrict__ csr_src,
                                               const float* __restrict__ al_s,
                                               const float* __restrict__ al_d,
                                               const float* __restrict__ b3,
                                               float* __restrict__ out) {
  __shared__ int   lsrc[4][CAP + 1];
  __shared__ float lew[4][6][CAP + 1];
  __shared__ float lasc[4][6];
  __shared__ float lrr[4][6];
  __shared__ float red[4][384];
  AGG_CORE(feat, off, csr_src, al_s, al_d)
  red[sub][c4 + 0] = a0 * rr;
  red[sub][c4 + 1] = a1 * rr;
  red[sub][c4 + 2] = a2 * rr;
  red[sub][c4 + 3] = a3 * rr;
  __syncthreads();
  if (t96 < 16) {
    int c = t96 * 4;
    f32x4 o = (f32x4)0.0f;
#pragma unroll
    for (int hh = 0; hh < HEADS; hh++) {
#pragma unroll
      for (int j = 0; j < 4; j++) o[j] += red[sub][hh * CH + c + j];
    }
#pragma unroll
    for (int j = 0; j < 4; j++) o[j] = o[j] * (1.0f / 6.0f) + b3[c + j];
    *(f32x4*)(out + (size_t)n * CH + c) = o;
  }
}

extern "C" void kernel_launch(void* const* d_in, const int* in_sizes, int n_in,
                              void* d_out, int out_size, void* d_ws, size_t ws_size,
                              hipStream_t stream) {
  const float* x  = (const float*)d_in[0];
  const int*   ei = (const int*)d_in[1];
  const float* W_[4]  = {(const float*)d_in[2], (const float*)d_in[6],
                         (const float*)d_in[10], (const float*)d_in[14]};
  const float* AS_[4] = {(const float*)d_in[3], (const float*)d_in[7],
                         (const float*)d_in[11], (const float*)d_in[15]};
  const float* AD_[4] = {(const float*)d_in[4], (const float*)d_in[8],
                         (const float*)d_in[12], (const float*)d_in[16]};
  const float* B_[4]  = {(const float*)d_in[5], (const float*)d_in[9],
                         (const float*)d_in[13], (const float*)d_in[17]};
  float* out = (float*)d_out;

  // ---- workspace layout ----
  char* w = (char*)d_ws;
  _Float16* feat = (_Float16*)w;                  // [N,384] fp16 GEMM out
  w += (size_t)N_NODES * F_HID * 2;
  char* Apk = w;                                  // fp16 A plane, chunk-major
  w += (size_t)NBM * ATILE3;
  char* Wt0 = w; w += 3 * (size_t)BTILE0;
  char* Wt1 = w; w += 3 * (size_t)BTILE3;
  char* Wt2 = w; w += 3 * (size_t)BTILE3;
  char* Wt3 = w; w += 3 * (size_t)BTILE3;
  float* als = (float*)w; w += (size_t)N_NODES * HEADS * 4;
  float* ald = (float*)w; w += (size_t)N_NODES * HEADS * 4;
  int* off = (int*)w; w += (N_NODES + 1) * 4;
  int* cur = (int*)w; w += N_NODES * 4;
  int* deg = (int*)w; w += N_NODES * 4;
  int* csr = (int*)w;

  // ---- CSR build ----
  (void)hipMemsetAsync(deg, 0, N_NODES * sizeof(int), stream);
  count_kernel<<<cdiv(N_EDGES, 256), 256, 0, stream>>>(ei, deg);
  scan_kernel<<<1, 256, 0, stream>>>(deg, off);
  (void)hipMemcpyAsync(cur, off, N_NODES * sizeof(int), hipMemcpyDeviceToDevice, stream);
  scatter_kernel<<<cdiv(N_EDGES, 256), 256, 0, stream>>>(ei, cur, csr);

  // ---- pack inputs ----
  convert_x<<<cdiv(M_PAD * (K0PAD / 8), 256), 256, 0, stream>>>(x, Apk);
  convert_W0<<<cdiv(F_HID * (K0PAD / 8), 256), 256, 0, stream>>>(W_[0], Wt0);
  {
    dim3 g(cdiv(F_HID * (F_HID / 8), 256), 3);
    convert_W123<<<g, 256, 0, stream>>>(W_[1], W_[2], W_[3], Wt1, Wt2, Wt3);
  }
  zero_padA<<<cdiv(48 * 48, 256), 256, 0, stream>>>(Apk);

  const int gemm_grid = 8 * cdiv(NBM, 8) * 3;  // XCD-grouped
  const int agg_grid = N_NODES / 4;            // 12500

  // ---- Layer 0 (K=160 packed) ----
  gemm_mfma<K0PAD><<<gemm_grid, 256, 0, stream>>>(Apk, Wt0, AS_[0], AD_[0], als, ald, feat);
  agg_hidden<<<agg_grid, 384, 0, stream>>>(feat, off, csr, als, ald, B_[0], Apk);

  // ---- Layers 1,2 (K=384) ----
  gemm_mfma<F_HID><<<gemm_grid, 256, 0, stream>>>(Apk, Wt1, AS_[1], AD_[1], als, ald, feat);
  agg_hidden<<<agg_grid, 384, 0, stream>>>(feat, off, csr, als, ald, B_[1], Apk);

  gemm_mfma<F_HID><<<gemm_grid, 256, 0, stream>>>(Apk, Wt2, AS_[2], AD_[2], als, ald, feat);
  agg_hidden<<<agg_grid, 384, 0, stream>>>(feat, off, csr, als, ald, B_[2], Apk);

  // ---- Layer 3 (K=384, mean over heads) ----
  gemm_mfma<F_HID><<<gemm_grid, 256, 0, stream>>>(Apk, Wt3, AS_[3], AD_[3], als, ald, feat);
  agg_out<<<agg_grid, 384, 0, stream>>>(feat, off, csr, als, ald, B_[3], out);
}

// Round 11
// 612.448 us; speedup vs baseline: 1.2982x; 1.0807x over previous
//
#include <hip/hip_runtime.h>

#define N_NODES 50000
#define M_PAD 50048      // N_NODES rounded up to 128
#define N_EDGES 500000
#define HEADS 6
#define CH 64
#define F_HID 384
#define IN_DIM 131
#define K0PAD 160        // layer-0 K padded to multiple of 32
#define CAP 64           // fast-path max degree
#define NBM 391          // cdiv(N_NODES,128)
#define ATILE3 98304     // (384/32)*8192 bytes per 128-row fp16 A tile
#define ATILE0 40960     // (160/32)*8192
#define BTILE3 98304     // (384/32)*8192 per 128-col fp16 B tile
#define BTILE0 40960

static inline int cdiv(int a, int b) { return (a + b - 1) / b; }

typedef __attribute__((ext_vector_type(4))) float f32x4;
typedef __attribute__((ext_vector_type(8))) _Float16 f16x8;
typedef __attribute__((ext_vector_type(4))) _Float16 f16x4;

__device__ __forceinline__ void gload16(const void* g, void* lds) {
  __builtin_amdgcn_global_load_lds((const __attribute__((address_space(1))) void*)g,
                                   (__attribute__((address_space(3))) void*)lds, 16, 0, 0);
}

// ---------------- CSR build ----------------
__global__ void count_kernel(const int* __restrict__ ei, int* __restrict__ deg) {
  int e = blockIdx.x * blockDim.x + threadIdx.x;
  if (e < N_EDGES) atomicAdd(&deg[ei[N_EDGES + e]], 1);
}

__global__ void scan_kernel(const int* __restrict__ deg, int* __restrict__ off) {
  __shared__ int sdata[256];
  int tid = threadIdx.x;
  int carry = 0;
  if (tid == 0) off[0] = 0;
  for (int base = 0; base < N_NODES; base += 1024) {
    int idx0 = base + tid * 4;
    int v[4]; int s = 0;
#pragma unroll
    for (int j = 0; j < 4; j++) {
      v[j] = (idx0 + j < N_NODES) ? deg[idx0 + j] : 0;
      s += v[j];
    }
    sdata[tid] = s;
    __syncthreads();
    for (int o = 1; o < 256; o <<= 1) {
      int x = (tid >= o) ? sdata[tid - o] : 0;
      __syncthreads();
      sdata[tid] += x;
      __syncthreads();
    }
    int excl = sdata[tid] - s + carry;
    int total = sdata[255];
    int run = excl;
#pragma unroll
    for (int j = 0; j < 4; j++) {
      run += v[j];
      if (idx0 + j < N_NODES) off[idx0 + j + 1] = run;
    }
    carry += total;
    __syncthreads();
  }
}

__global__ void scatter_kernel(const int* __restrict__ ei, int* __restrict__ cursor,
                               int* __restrict__ csr_src) {
  int e = blockIdx.x * blockDim.x + threadIdx.x;
  if (e < N_EDGES) {
    int d = ei[N_EDGES + e];
    int p = atomicAdd(&cursor[d], 1);
    csr_src[p] = ei[e];
  }
}

// ---------------- packers (chunk-major layout) ----------------
// A plane: [tile=r>>7][kt][kb][r&127] 16B chunks (8 fp16 = k's kt*32+kb*8 .. +7).
__global__ void convert_x(const float* __restrict__ x, char* __restrict__ Apk) {
  int t = blockIdx.x * blockDim.x + threadIdx.x;
  const int npc = K0PAD / 8;  // 20
  if (t >= M_PAD * npc) return;
  int r = t / npc, g = t % npc;
  int kt = g >> 2, kb = g & 3;
  int k0 = kt * 32 + kb * 8;
  f16x8 hv;
#pragma unroll
  for (int j = 0; j < 8; j++) {
    int k = k0 + j;
    float v = (r < N_NODES && k < IN_DIM) ? x[(long)r * IN_DIM + k] : 0.0f;
    hv[j] = (_Float16)v;
  }
  *(f16x8*)(Apk + (size_t)(r >> 7) * ATILE0 + kt * 8192 + kb * 2048 + (r & 127) * 16) = hv;
}

// zero the pad rows (50000..50047) of the K=384 A plane once per call
__global__ void zero_padA(char* __restrict__ Apk) {
  int t = blockIdx.x * blockDim.x + threadIdx.x;
  if (t >= 48 * 48) return;
  int chunk = t / 48, r = 80 + t % 48;
  int kt = chunk >> 2, kb = chunk & 3;
  *(f32x4*)(Apk + (size_t)390 * ATILE3 + kt * 8192 + kb * 2048 + r * 16) = (f32x4)0.0f;
}

// B plane (W^T fp16): [bn=n>>7][kt][kb][col=n&127] 16B chunks.
__global__ void convert_W0(const float* __restrict__ W, char* __restrict__ Wt) {
  int t = blockIdx.x * blockDim.x + threadIdx.x;
  const int npc = K0PAD >> 3;
  if (t >= F_HID * npc) return;
  int n = t / npc, g = t % npc;
  int kt = g >> 2, kb = g & 3;
  int k0 = kt * 32 + kb * 8;
  f16x8 hv;
#pragma unroll
  for (int j = 0; j < 8; j++) {
    int k = k0 + j;
    float v = (k < IN_DIM) ? W[(long)k * F_HID + n] : 0.0f;
    hv[j] = (_Float16)v;
  }
  *(f16x8*)(Wt + (size_t)(n >> 7) * BTILE0 + kt * 8192 + kb * 2048 + (n & 127) * 16) = hv;
}

__global__ void convert_W123(const float* __restrict__ W1, const float* __restrict__ W2,
                             const float* __restrict__ W3, char* __restrict__ Wt1,
                             char* __restrict__ Wt2, char* __restrict__ Wt3) {
  int t = blockIdx.x * blockDim.x + threadIdx.x;
  const int npc = F_HID >> 3;
  if (t >= F_HID * npc) return;
  const float* W = blockIdx.y == 0 ? W1 : (blockIdx.y == 1 ? W2 : W3);
  char* Wt = blockIdx.y == 0 ? Wt1 : (blockIdx.y == 1 ? Wt2 : Wt3);
  int n = t / npc, g = t % npc;
  int kt = g >> 2, kb = g & 3;
  int k0 = kt * 32 + kb * 8;
  f16x8 hv;
#pragma unroll
  for (int j = 0; j < 8; j++) hv[j] = (_Float16)W[(long)(k0 + j) * F_HID + n];
  *(f16x8*)(Wt + (size_t)(n >> 7) * BTILE3 + kt * 8192 + kb * 2048 + (n & 127) * 16) = hv;
}

// ---------------- fp16 MFMA GEMM + fused attention dots ----------------
template <int K>
__global__ __launch_bounds__(256) void gemm_mfma(const char* __restrict__ Ap,
                                                 const char* __restrict__ Bp,
                                                 const float* __restrict__ AS,
                                                 const float* __restrict__ AD,
                                                 float* __restrict__ als,
                                                 float* __restrict__ ald,
                                                 _Float16* __restrict__ O) {
  constexpr int NKT = K / 32;
  __shared__ __align__(16) char smA[8192];
  __shared__ __align__(16) char smB[8192];
  int xcd = blockIdx.x & 7, slot = blockIdx.x >> 3;
  int bn = slot % 3, tt = slot / 3;
  int bm = tt * 8 + xcd;
  if (bm >= NBM) return;
  int row0 = bm * 128, col0 = bn * 128;
  int tid = threadIdx.x, lane = tid & 63, wv = tid >> 6;
  int wy = wv >> 1, wx = wv & 1;

  f32x4 acc[4][4];
#pragma unroll
  for (int i = 0; i < 4; i++)
#pragma unroll
    for (int j = 0; j < 4; j++) acc[i][j] = (f32x4)0.0f;

  const char* Ab = Ap + (size_t)bm * (NKT * 8192);
  const char* Bb = Bp + (size_t)bn * (NKT * 8192);
  int rsel = lane & 15, ksel = lane >> 4;

  for (int kt = 0; kt < NKT; ++kt) {
    // stage 8KB A + 8KB B, linear (chunk-major => conflict-free ds_read)
#pragma unroll
    for (int i = 0; i < 2; ++i) {
      int b = (i * 4 + wv) * 1024;
      gload16(Ab + (size_t)kt * 8192 + b + lane * 16, smA + b);
      gload16(Bb + (size_t)kt * 8192 + b + lane * 16, smB + b);
    }
    __syncthreads();

    f16x8 av[4], bv[4];
#pragma unroll
    for (int mf = 0; mf < 4; ++mf)
      av[mf] = *(const f16x8*)(smA + ksel * 2048 + (wy * 64 + mf * 16 + rsel) * 16);
#pragma unroll
    for (int nf = 0; nf < 4; ++nf)
      bv[nf] = *(const f16x8*)(smB + ksel * 2048 + (wx * 64 + nf * 16 + rsel) * 16);
#pragma unroll
    for (int mf = 0; mf < 4; ++mf)
#pragma unroll
      for (int nf = 0; nf < 4; ++nf)
        acc[mf][nf] = __builtin_amdgcn_mfma_f32_16x16x32_f16(av[mf], bv[nf], acc[mf][nf], 0, 0, 0);
    __syncthreads();
  }

  int cr = (lane >> 4) * 4, cc = lane & 15;
#pragma unroll
  for (int mf = 0; mf < 4; ++mf)
#pragma unroll
    for (int r = 0; r < 4; ++r) {
      int row = row0 + wy * 64 + mf * 16 + cr + r;
      if (row < N_NODES) {
#pragma unroll
        for (int nf = 0; nf < 4; ++nf)
          O[(size_t)row * F_HID + col0 + wx * 64 + nf * 16 + cc] = (_Float16)acc[mf][nf][r];
      }
    }
  // fused dots: head = 2*bn + wx; this wave holds its full 64 cols
  int head = bn * 2 + wx;
  float sa[4], da[4];
#pragma unroll
  for (int nf = 0; nf < 4; ++nf) {
    sa[nf] = AS[head * CH + nf * 16 + cc];
    da[nf] = AD[head * CH + nf * 16 + cc];
  }
#pragma unroll
  for (int mf = 0; mf < 4; ++mf)
#pragma unroll
    for (int r = 0; r < 4; ++r) {
      float ps = 0.0f, pd = 0.0f;
#pragma unroll
      for (int nf = 0; nf < 4; ++nf) {
        ps += acc[mf][nf][r] * sa[nf];
        pd += acc[mf][nf][r] * da[nf];
      }
#pragma unroll
      for (int o = 1; o < 16; o <<= 1) {
        ps += __shfl_xor(ps, o);
        pd += __shfl_xor(pd, o);
      }
      int row = row0 + wy * 64 + mf * 16 + cr + r;
      if (cc == 0 && row < N_NODES) {
        als[row * HEADS + head] = ps;
        ald[row * HEADS + head] = pd;
      }
    }
}

// ---------------- phase-split agg core (R8-proven: 4 nodes x 96 thr) ----------
typedef __attribute__((ext_vector_type(4))) _Float16 f16x4t;
#define AGG_CORE(FEAT, OFF, CSR, ALS, ALD)                                        \
  int tid = threadIdx.x;                                                          \
  int sub = tid / 96, t96 = tid - sub * 96;                                       \
  int nb = blockIdx.x * 4;                                                        \
  int n = nb + sub;                                                               \
  int c4 = t96 * 4, h = t96 >> 4;                                                 \
  int o_[5];                                                                      \
  _Pragma("unroll")                                                               \
  for (int k = 0; k < 5; ++k) o_[k] = OFF[nb + k];                                \
  int dmax = 0;                                                                   \
  _Pragma("unroll")                                                               \
  for (int k = 0; k < 4; ++k) dmax = max(dmax, o_[k + 1] - o_[k]);                \
  int nch = (dmax + CAP - 1) / CAP; if (nch < 1) nch = 1;                         \
  int s0 = o_[sub], deg = o_[sub + 1] - o_[sub];                                  \
  int pr = tid >> 4, pl = tid & 15;                                               \
  int psub = pr / 6, ph = pr - psub * 6;                                          \
  int pdeg = o_[psub + 1] - o_[psub];                                             \
  float m_run = -INFINITY, s_run = 0.0f;                                          \
  float a0 = 0, a1 = 0, a2 = 0, a3 = 0;                                           \
  for (int ch = 0; ch < nch; ++ch) {                                              \
    int base = ch * CAP;                                                          \
    int cl = deg - base; cl = cl < 0 ? 0 : (cl > CAP ? CAP : cl);                 \
    if (t96 < cl) lsrc[sub][t96] = CSR[s0 + base + t96];                          \
    for (int j = t96; j < cl * 6; j += 96) {                                      \
      int i = j / 6, hh = j - i * 6;                                              \
      int s = CSR[s0 + base + i];                                                 \
      float e = ALS[s * 6 + hh] + ALD[n * 6 + hh];                                \
      e = e > 0.0f ? e : 0.2f * e;                                                \
      lew[sub][hh][i] = e;                                                        \
    }                                                                             \
    __syncthreads();                                                              \
    int pcl = pdeg - base; pcl = pcl < 0 ? 0 : (pcl > CAP ? CAP : pcl);           \
    float asc = 1.0f;                                                             \
    if (pcl > 0) {                                                                \
      float mc = -INFINITY;                                                       \
      for (int i = pl; i < pcl; i += 16) mc = fmaxf(mc, lew[psub][ph][i]);        \
      mc = fmaxf(mc, __shfl_xor(mc, 1));                                          \
      mc = fmaxf(mc, __shfl_xor(mc, 2));                                          \
      mc = fmaxf(mc, __shfl_xor(mc, 4));                                          \
      mc = fmaxf(mc, __shfl_xor(mc, 8));                                          \
      float mn = fmaxf(m_run, mc);                                                \
      asc = (m_run == -INFINITY) ? 0.0f : __expf(m_run - mn);                     \
      float scp = 0.0f;                                                           \
      for (int i = pl; i < pcl; i += 16) {                                        \
        float wv = __expf(lew[psub][ph][i] - mn);                                 \
        lew[psub][ph][i] = wv;                                                    \
        scp += wv;                                                                \
      }                                                                           \
      scp += __shfl_xor(scp, 1);                                                  \
      scp += __shfl_xor(scp, 2);                                                  \
      scp += __shfl_xor(scp, 4);                                                  \
      scp += __shfl_xor(scp, 8);                                                  \
      s_run = s_run * asc + scp;                                                  \
      m_run = mn;                                                                 \
    }                                                                             \
    if (pl == 0) {                                                                \
      lasc[psub][ph] = asc;                                                       \
      if (ch == nch - 1) lrr[psub][ph] = 1.0f / (s_run + 1e-16f);                 \
    }                                                                             \
    __syncthreads();                                                              \
    float cc0 = 0, cc1 = 0, cc2 = 0, cc3 = 0;                                     \
    int i = 0;                                                                    \
    for (; i + 4 <= cl; i += 4) {                                                 \
      int sA = lsrc[sub][i], sB = lsrc[sub][i + 1];                               \
      int sC = lsrc[sub][i + 2], sD = lsrc[sub][i + 3];                           \
      float wA = lew[sub][h][i], wB = lew[sub][h][i + 1];                         \
      float wC = lew[sub][h][i + 2], wD = lew[sub][h][i + 3];                     \
      f16x4t fA = *(const f16x4t*)(FEAT + (size_t)sA * F_HID + c4);               \
      f16x4t fB = *(const f16x4t*)(FEAT + (size_t)sB * F_HID + c4);               \
      f16x4t fC = *(const f16x4t*)(FEAT + (size_t)sC * F_HID + c4);               \
      f16x4t fD = *(const f16x4t*)(FEAT + (size_t)sD * F_HID + c4);               \
      cc0 += wA * (float)fA[0]; cc1 += wA * (float)fA[1];                         \
      cc2 += wA * (float)fA[2]; cc3 += wA * (float)fA[3];                         \
      cc0 += wB * (float)fB[0]; cc1 += wB * (float)fB[1];                         \
      cc2 += wB * (float)fB[2]; cc3 += wB * (float)fB[3];                         \
      cc0 += wC * (float)fC[0]; cc1 += wC * (float)fC[1];                         \
      cc2 += wC * (float)fC[2]; cc3 += wC * (float)fC[3];                         \
      cc0 += wD * (float)fD[0]; cc1 += wD * (float)fD[1];                         \
      cc2 += wD * (float)fD[2]; cc3 += wD * (float)fD[3];                         \
    }                                                                             \
    for (; i < cl; ++i) {                                                         \
      int s = lsrc[sub][i];                                                       \
      float wv = lew[sub][h][i];                                                  \
      f16x4t fv = *(const f16x4t*)(FEAT + (size_t)s * F_HID + c4);                \
      cc0 += wv * (float)fv[0]; cc1 += wv * (float)fv[1];                         \
      cc2 += wv * (float)fv[2]; cc3 += wv * (float)fv[3];                         \
    }                                                                             \
    float asc2 = lasc[sub][h];                                                    \
    a0 = a0 * asc2 + cc0; a1 = a1 * asc2 + cc1;                                   \
    a2 = a2 * asc2 + cc2; a3 = a3 * asc2 + cc3;                                   \
    __syncthreads();                                                              \
  }                                                                               \
  float rr = lrr[sub][h];

// hidden layers: normalize + bias + ELU + fp16 pack (chunk-major A plane)
__global__ __launch_bounds__(384) void agg_hidden(const _Float16* __restrict__ feat,
                                                  const int* __restrict__ off,
                                                  const int* __restrict__ csr_src,
                                                  const float* __restrict__ al_s,
                                                  const float* __restrict__ al_d,
                                                  const float* __restrict__ bias,
                                                  char* __restrict__ Apk) {
  __shared__ int   lsrc[4][CAP + 1];
  __shared__ float lew[4][6][CAP + 1];
  __shared__ float lasc[4][6];
  __shared__ float lrr[4][6];
  AGG_CORE(feat, off, csr_src, al_s, al_d)
  float v0 = a0 * rr + bias[c4 + 0];
  float v1 = a1 * rr + bias[c4 + 1];
  float v2 = a2 * rr + bias[c4 + 2];
  float v3 = a3 * rr + bias[c4 + 3];
  v0 = v0 > 0.0f ? v0 : (__expf(v0) - 1.0f);
  v1 = v1 > 0.0f ? v1 : (__expf(v1) - 1.0f);
  v2 = v2 > 0.0f ? v2 : (__expf(v2) - 1.0f);
  v3 = v3 > 0.0f ? v3 : (__expf(v3) - 1.0f);
  f16x4 pv;
  pv[0] = (_Float16)v0; pv[1] = (_Float16)v1;
  pv[2] = (_Float16)v2; pv[3] = (_Float16)v3;
  int kt = c4 >> 5, kb = (c4 >> 3) & 3, j = c4 & 7;
  *(f16x4*)(Apk + (size_t)(n >> 7) * ATILE3 + kt * 8192 + kb * 2048 +
            (n & 127) * 16 + j * 2) = pv;
}

// output layer: normalize + head-mean + bias
__global__ __launch_bounds__(384) void agg_out(const _Float16* __restrict__ feat,
                                               const int* __restrict__ off,
                                               const int* __restrict__ csr_src,
                                               const float* __restrict__ al_s,
                                               const float* __restrict__ al_d,
                                               const float* __restrict__ b3,
                                               float* __restrict__ out) {
  __shared__ int   lsrc[4][CAP + 1];
  __shared__ float lew[4][6][CAP + 1];
  __shared__ float lasc[4][6];
  __shared__ float lrr[4][6];
  __shared__ float red[4][384];
  AGG_CORE(feat, off, csr_src, al_s, al_d)
  red[sub][c4 + 0] = a0 * rr;
  red[sub][c4 + 1] = a1 * rr;
  red[sub][c4 + 2] = a2 * rr;
  red[sub][c4 + 3] = a3 * rr;
  __syncthreads();
  if (t96 < 16) {
    int c = t96 * 4;
    f32x4 o = (f32x4)0.0f;
#pragma unroll
    for (int hh = 0; hh < HEADS; hh++) {
#pragma unroll
      for (int j = 0; j < 4; j++) o[j] += red[sub][hh * CH + c + j];
    }
#pragma unroll
    for (int j = 0; j < 4; j++) o[j] = o[j] * (1.0f / 6.0f) + b3[c + j];
    *(f32x4*)(out + (size_t)n * CH + c) = o;
  }
}

extern "C" void kernel_launch(void* const* d_in, const int* in_sizes, int n_in,
                              void* d_out, int out_size, void* d_ws, size_t ws_size,
                              hipStream_t stream) {
  const float* x  = (const float*)d_in[0];
  const int*   ei = (const int*)d_in[1];
  const float* W_[4]  = {(const float*)d_in[2], (const float*)d_in[6],
                         (const float*)d_in[10], (const float*)d_in[14]};
  const float* AS_[4] = {(const float*)d_in[3], (const float*)d_in[7],
                         (const float*)d_in[11], (const float*)d_in[15]};
  const float* AD_[4] = {(const float*)d_in[4], (const float*)d_in[8],
                         (const float*)d_in[12], (const float*)d_in[16]};
  const float* B_[4]  = {(const float*)d_in[5], (const float*)d_in[9],
                         (const float*)d_in[13], (const float*)d_in[17]};
  float* out = (float*)d_out;

  // ---- workspace layout ----
  char* w = (char*)d_ws;
  _Float16* feat = (_Float16*)w;                  // [N,384] fp16 GEMM out
  w += (size_t)N_NODES * F_HID * 2;
  char* Apk = w;                                  // fp16 A plane, chunk-major
  w += (size_t)NBM * ATILE3;
  char* Wt0 = w; w += 3 * (size_t)BTILE0;
  char* Wt1 = w; w += 3 * (size_t)BTILE3;
  char* Wt2 = w; w += 3 * (size_t)BTILE3;
  char* Wt3 = w; w += 3 * (size_t)BTILE3;
  float* als = (float*)w; w += (size_t)N_NODES * HEADS * 4;
  float* ald = (float*)w; w += (size_t)N_NODES * HEADS * 4;
  int* off = (int*)w; w += (N_NODES + 1) * 4;
  int* cur = (int*)w; w += N_NODES * 4;
  int* deg = (int*)w; w += N_NODES * 4;
  int* csr = (int*)w;

  // ---- CSR build ----
  (void)hipMemsetAsync(deg, 0, N_NODES * sizeof(int), stream);
  count_kernel<<<cdiv(N_EDGES, 256), 256, 0, stream>>>(ei, deg);
  scan_kernel<<<1, 256, 0, stream>>>(deg, off);
  (void)hipMemcpyAsync(cur, off, N_NODES * sizeof(int), hipMemcpyDeviceToDevice, stream);
  scatter_kernel<<<cdiv(N_EDGES, 256), 256, 0, stream>>>(ei, cur, csr);

  // ---- pack inputs ----
  convert_x<<<cdiv(M_PAD * (K0PAD / 8), 256), 256, 0, stream>>>(x, Apk);
  convert_W0<<<cdiv(F_HID * (K0PAD / 8), 256), 256, 0, stream>>>(W_[0], Wt0);
  {
    dim3 g(cdiv(F_HID * (F_HID / 8), 256), 3);
    convert_W123<<<g, 256, 0, stream>>>(W_[1], W_[2], W_[3], Wt1, Wt2, Wt3);
  }
  zero_padA<<<cdiv(48 * 48, 256), 256, 0, stream>>>(Apk);

  const int gemm_grid = 8 * cdiv(NBM, 8) * 3;  // XCD-grouped
  const int agg_grid = N_NODES / 4;            // 12500

  // ---- Layer 0 (K=160 packed) ----
  gemm_mfma<K0PAD><<<gemm_grid, 256, 0, stream>>>(Apk, Wt0, AS_[0], AD_[0], als, ald, feat);
  agg_hidden<<<agg_grid, 384, 0, stream>>>(feat, off, csr, als, ald, B_[0], Apk);

  // ---- Layers 1,2 (K=384) ----
  gemm_mfma<F_HID><<<gemm_grid, 256, 0, stream>>>(Apk, Wt1, AS_[1], AD_[1], als, ald, feat);
  agg_hidden<<<agg_grid, 384, 0, stream>>>(feat, off, csr, als, ald, B_[1], Apk);

  gemm_mfma<F_HID><<<gemm_grid, 256, 0, stream>>>(Apk, Wt2, AS_[2], AD_[2], als, ald, feat);
  agg_hidden<<<agg_grid, 384, 0, stream>>>(feat, off, csr, als, ald, B_[2], Apk);

  // ---- Layer 3 (K=384, mean over heads) ----
  gemm_mfma<F_HID><<<gemm_grid, 256, 0, stream>>>(Apk, Wt3, AS_[3], AD_[3], als, ald, feat);
  agg_out<<<agg_grid, 384, 0, stream>>>(feat, off, csr, als, ald, B_[3], out);
}